// Round 1
// 982.388 us; speedup vs baseline: 1.1244x; 1.1244x over previous
//
#include <hip/hip_runtime.h>
#include <math.h>

#define EPSBN 1e-5f

typedef __fp16 h2 __attribute__((ext_vector_type(2)));
typedef __attribute__((address_space(1))) const void gv_t;
typedef __attribute__((address_space(3))) void lv_t;

__device__ inline unsigned pkrtz(float a, float b) {
  h2 r = __builtin_amdgcn_cvt_pkrtz(a, b);
  return __builtin_bit_cast(unsigned, r);
}

#if defined(__has_builtin) && __has_builtin(__builtin_amdgcn_fdot2)
__device__ inline float dot2(unsigned a, unsigned b, float c) {
  return __builtin_amdgcn_fdot2(__builtin_bit_cast(h2, a),
                                __builtin_bit_cast(h2, b), c, false);
}
#else
__device__ inline float dot2(unsigned a, unsigned b, float c) {
  h2 ha = __builtin_bit_cast(h2, a), hb = __builtin_bit_cast(h2, b);
  return c + (float)ha[0] * (float)hb[0] + (float)ha[1] * (float)hb[1];
}
#endif

__device__ inline void stage16(const unsigned short* g, unsigned short* l, int lane) {
#if defined(__has_builtin) && __has_builtin(__builtin_amdgcn_global_load_lds)
  __builtin_amdgcn_global_load_lds((gv_t*)(g + lane * 8), (lv_t*)l, 16, 0, 0);
#else
  *(uint4*)(l + lane * 8) = *(const uint4*)(g + lane * 8);
#endif
}

__device__ inline float eluf(float x) { return x > 0.f ? x : expm1f(x); }

// ---------------- v = inputs @ W_in + b_in, fused elu-stats partials -----
// grid 512x256 covers exactly 2*1024*64 elements (4 rows x 64 ch per block)
__global__ void k_in(const float* __restrict__ inp, const float* __restrict__ Win,
                     const float* __restrict__ bin, float* __restrict__ v,
                     float* __restrict__ pv) {
  __shared__ float s1s[4][64], s2s[4][64];
  int tid = threadIdx.x;
  int g = blockIdx.x * 256 + tid;
  int row = g >> 6, c = g & 63, ns = tid >> 6;
  float s = bin[c] + inp[row * 3 + 0] * Win[c] + inp[row * 3 + 1] * Win[64 + c] +
            inp[row * 3 + 2] * Win[128 + c];
  v[g] = s;
  float e = eluf(s);
  s1s[ns][c] = e; s2s[ns][c] = e * e;
  __syncthreads();
  if (tid < 128) {
    int c2 = tid & 63;
    float t = (tid < 64) ? s1s[0][c2] + s1s[1][c2] + s1s[2][c2] + s1s[3][c2]
                         : s2s[0][c2] + s2s[1][c2] + s2s[2][c2] + s2s[3][c2];
    atomicAdd(&pv[(blockIdx.x & 31) * 128 + tid], t);
  }
}

// ---------------- BN(elu(z)) @ W + b, elu, write X^T fp16 [b][j][k] ------
// part: 32x128 atomic partials from the producer of z.
__global__ __launch_bounds__(256) void k_transform(
    const float* __restrict__ z, const float* __restrict__ part,
    const float* __restrict__ gamma, const float* __restrict__ beta,
    const float* __restrict__ W, const float* __restrict__ bias,
    unsigned short* __restrict__ Xt, int R, int Kx) {
  __shared__ float ab[2][64];
  __shared__ float xn[4][64];
  __shared__ float red[128];
  int tid = threadIdx.x, c = tid & 63, ns = tid >> 6;
  float wc[64];  // column c of W, statically indexed -> stays in VGPRs
#pragma unroll
  for (int d = 0; d < 64; ++d) wc[d] = W[d * 64 + c];
  if (tid < 128) {
    float s = 0.f;
#pragma unroll
    for (int g2 = 0; g2 < 32; ++g2) s += part[g2 * 128 + tid];
    red[tid] = s;
  }
  __syncthreads();
  if (tid < 64) {
    float m = red[tid] / (float)R;
    float var = red[64 + tid] / (float)R - m * m;
    float a = gamma[tid] * rsqrtf(var + EPSBN);
    ab[0][tid] = a; ab[1][tid] = beta[tid] - m * a;
  }
  __syncthreads();
  float biasc = bias[c];
  int rpb = R >> 1;
  for (int rowg = blockIdx.x; rowg * 4 < R; rowg += gridDim.x) {
    int row = rowg * 4 + ns;
    float t = eluf(z[row * 64 + c]);
    xn[ns][c] = t * ab[0][c] + ab[1][c];
    __syncthreads();
    float acc = biasc;
#pragma unroll
    for (int d4 = 0; d4 < 16; ++d4) {
      float4 xv = *(const float4*)&xn[ns][d4 * 4];
      acc += xv.x * wc[4 * d4] + xv.y * wc[4 * d4 + 1] + xv.z * wc[4 * d4 + 2] +
             xv.w * wc[4 * d4 + 3];
    }
    float o = eluf(acc);
    int b = row >= rpb ? 1 : 0;
    int n = row - b * rpb;
    _Float16 oh = (_Float16)o;
    Xt[(size_t)b * 16 * Kx + (size_t)(c & 15) * Kx + 4 * n + (c >> 4)] =
        __builtin_bit_cast(unsigned short, oh);
    __syncthreads();
  }
}

// ---------------- out[m][j] (+)= sum_k D[m][k]*X[j][k]  (the HBM stream) -
// MODE 0: load D fp32.  MODE 1: load fp32, also store fp16 copy.  MODE 2: load fp16.
// ZERO 1: overwrite out (skip the += read).  Fused elu-stats of the FINAL
// out values -> atomic partials in statp; also zeroes zbuf (the OTHER stat
// buffer, already consumed by the preceding k_transform) for the next stage.
template <int MODE, int ZERO>
__global__ __launch_bounds__(256, 4) void k_bigmat(const float* __restrict__ Df,
                                                   unsigned short* __restrict__ D16,
                                                   const unsigned short* __restrict__ Xt,
                                                   float* __restrict__ out, int M, int K,
                                                   float* __restrict__ statp,
                                                   float* __restrict__ zbuf) {
  __shared__ __align__(16) unsigned char smem[33792];
  __shared__ float st1[4][64], st2[4][64];
  unsigned short* xs = (unsigned short*)smem;  // [2][16][520] halves
  int tid = threadIdx.x;
  if (tid < 128 && blockIdx.y == 0 && blockIdx.x < 32)
    zbuf[blockIdx.x * 128 + tid] = 0.f;
  int wv = tid >> 6, lane = tid & 63;
  int b = blockIdx.y;
  size_t bstr = (size_t)M * (size_t)K;
  const float* df = Df + (size_t)b * bstr;
  unsigned short* d16 = D16 + (MODE == 0 ? 0 : (size_t)b * bstr);
  const unsigned short* xg = Xt + (size_t)b * 16 * K;
  float* ob = out + (size_t)b * M * 16;
  int row0 = blockIdx.x * 16 + wv * 4;

  float acc[4][16];
#pragma unroll
  for (int r = 0; r < 4; r++) {
#pragma unroll
    for (int j = 0; j < 16; j++) acc[r][j] = 0.f;
  }
  const int nc = K >> 9;

  auto stage = [&](int buf, int chunk) {
    unsigned short* base = xs + buf * (16 * 520);
#pragma unroll
    for (int q = 0; q < 4; q++) {
      int j = wv * 4 + q;
      const unsigned short* g = xg + (size_t)j * K + chunk * 512;
      stage16(g, base + j * 520, lane);
    }
  };

  stage(0, 0);
  __syncthreads();
  for (int c = 0; c < nc; ++c) {
    if (c + 1 < nc) stage((c + 1) & 1, c + 1);
    const unsigned short* xb = xs + (c & 1) * (16 * 520);
    uint4 d[4];
#pragma unroll
    for (int r = 0; r < 4; r++) {
      size_t off = (size_t)(row0 + r) * K + c * 512 + lane * 8;
      if (MODE == 2) {
        d[r] = *(const uint4*)(d16 + off);
      } else {
        const float4 a = *(const float4*)(df + off);
        const float4 bb = *(const float4*)(df + off + 4);
        d[r].x = pkrtz(a.x, a.y); d[r].y = pkrtz(a.z, a.w);
        d[r].z = pkrtz(bb.x, bb.y); d[r].w = pkrtz(bb.z, bb.w);
        if (MODE == 1) *(uint4*)(d16 + off) = d[r];
      }
    }
#pragma unroll
    for (int j = 0; j < 16; j++) {
      const uint4 x = *(const uint4*)(xb + j * 520 + lane * 8);
#pragma unroll
      for (int r = 0; r < 4; r++) {
        acc[r][j] = dot2(d[r].x, x.x, acc[r][j]);
        acc[r][j] = dot2(d[r].y, x.y, acc[r][j]);
        acc[r][j] = dot2(d[r].z, x.z, acc[r][j]);
        acc[r][j] = dot2(d[r].w, x.w, acc[r][j]);
      }
    }
    __syncthreads();
  }

  // cross-lane reduction via (dead) staging LDS; region per wave = 2112 floats
  float* red = (float*)smem + wv * 2112;
#pragma unroll
  for (int t = 0; t < 2; t++) {
#pragma unroll
    for (int i = 0; i < 32; i++) red[lane * 33 + i] = acc[2 * t + (i >> 4)][i & 15];
    float s = 0.f;
    int ci = lane & 31, pb = (lane >> 5) * 32;
#pragma unroll
    for (int p = 0; p < 32; p++) s += red[(pb + p) * 33 + ci];
    s += __shfl_xor(s, 32);
    if (lane < 32) {
      int r = 2 * t + (lane >> 4), j = lane & 15;
      size_t oi = (size_t)(row0 + r) * 16 + j;
      float val = ZERO ? s : ob[oi] + s;
      ob[oi] = val;
      float e = eluf(val);
      int ch = ((r & 3) << 4) | j;  // row0 % 4 == 0, so channel = (r&3)*16+j
      st1[wv][ch] = e; st2[wv][ch] = e * e;
    }
  }
  __syncthreads();
  if (tid < 128) {
    int c2 = tid & 63;
    float t2 = (tid < 64) ? st1[0][c2] + st1[1][c2] + st1[2][c2] + st1[3][c2]
                          : st2[0][c2] + st2[1][c2] + st2[2][c2] + st2[3][c2];
    atomicAdd(&statp[(blockIdx.x & 31) * 128 + tid], t2);
  }
}

// ---------------- epilogue transform + masked pool partials --------------
__global__ void k_trans_pool(const float* __restrict__ z, const float* __restrict__ part,
                             const float* __restrict__ gamma, const float* __restrict__ beta,
                             const float* __restrict__ W, const float* __restrict__ bias,
                             const float* __restrict__ mask, float* __restrict__ pp) {
  const int R = 2048;
  __shared__ float ab[2][64];
  __shared__ float xn[4][64];
  __shared__ float rr[4][128];
  __shared__ float red[128];
  int tid = threadIdx.x, c = tid & 63, ns = tid >> 6;
  float wc[64];
#pragma unroll
  for (int d = 0; d < 64; ++d) wc[d] = W[d * 64 + c];
  if (tid < 128) {
    float s = 0.f;
#pragma unroll
    for (int g2 = 0; g2 < 32; ++g2) s += part[g2 * 128 + tid];
    red[tid] = s;
  }
  __syncthreads();
  if (tid < 64) {
    float m = red[tid] / (float)R;
    float var = red[64 + tid] / (float)R - m * m;
    float a = gamma[tid] * rsqrtf(var + EPSBN);
    ab[0][tid] = a; ab[1][tid] = beta[tid] - m * a;
  }
  __syncthreads();
  float biasc = bias[c];
  float po0 = 0.f, po1 = 0.f;
  for (int rowg = blockIdx.x; rowg * 4 < R; rowg += gridDim.x) {
    int row = rowg * 4 + ns;
    float t = eluf(z[row * 64 + c]);
    xn[ns][c] = t * ab[0][c] + ab[1][c];
    __syncthreads();
    float acc = biasc;
#pragma unroll
    for (int d4 = 0; d4 < 16; ++d4) {
      float4 xv = *(const float4*)&xn[ns][d4 * 4];
      acc += xv.x * wc[4 * d4] + xv.y * wc[4 * d4 + 1] + xv.z * wc[4 * d4 + 2] +
             xv.w * wc[4 * d4 + 3];
    }
    float o = eluf(acc) * mask[row];
    if (row < 1024) po0 += o; else po1 += o;
    __syncthreads();
  }
  rr[ns][c] = po0; rr[ns][64 + c] = po1;
  __syncthreads();
  if (tid < 128)
    pp[blockIdx.x * 128 + tid] = rr[0][tid] + rr[1][tid] + rr[2][tid] + rr[3][tid];
}

// ---------------- pooled @ Wfc + bfc, log_softmax ------------------------
__global__ void k_final(const float* __restrict__ pp, const float* __restrict__ mask,
                        const float* __restrict__ Wfc, const float* __restrict__ bfc,
                        float* __restrict__ outp) {
  __shared__ float pooled[128];
  __shared__ float msum[2];
  __shared__ float lg[20];
  __shared__ float msr[256];
  int tid = threadIdx.x;
  {
    int b2 = tid >> 7, st = tid & 127;
    float s = 0.f;
    for (int n = st; n < 1024; n += 128) s += mask[b2 * 1024 + n];
    msr[tid] = s;
  }
  __syncthreads();
  if (tid < 2) {
    float s = 0.f;
    for (int i = 0; i < 128; i++) s += msr[tid * 128 + i];
    msum[tid] = s;
  }
  __syncthreads();
  if (tid < 128) {
    float s = 0.f;
    for (int g = 0; g < 128; ++g) s += pp[g * 128 + tid];
    pooled[tid] = s / msum[tid >> 6];
  }
  __syncthreads();
  if (tid < 20) {
    int b2 = tid / 10, o = tid % 10;
    float s = bfc[o];
    for (int c2 = 0; c2 < 64; ++c2) s += pooled[b2 * 64 + c2] * Wfc[c2 * 10 + o];
    lg[tid] = s;
  }
  __syncthreads();
  if (tid < 2) {
    float m = -1e30f;
    for (int o = 0; o < 10; o++) m = fmaxf(m, lg[tid * 10 + o]);
    float se = 0.f;
    for (int o = 0; o < 10; o++) se += expf(lg[tid * 10 + o] - m);
    float ls = m + logf(se);
    for (int o = 0; o < 10; o++) outp[tid * 10 + o] = lg[tid * 10 + o] - ls;
  }
}

extern "C" void kernel_launch(void* const* d_in, const int* in_sizes, int n_in,
                              void* d_out, int out_size, void* d_ws, size_t ws_size,
                              hipStream_t stream) {
  (void)in_sizes; (void)n_in; (void)out_size;
  const float* inp  = (const float*)d_in[0];
  const float* Di   = (const float*)d_in[1];
  const float* DiA  = (const float*)d_in[2];
  const float* mask = (const float*)d_in[3];
  const float* Win  = (const float*)d_in[4];
  const float* bin  = (const float*)d_in[5];
  const float* W0   = (const float*)d_in[6];
  const float* b0   = (const float*)d_in[7];
  const float* g0   = (const float*)d_in[8];
  const float* be0  = (const float*)d_in[9];
  const float* W1   = (const float*)d_in[10];
  const float* b1   = (const float*)d_in[11];
  const float* g1   = (const float*)d_in[12];
  const float* be1  = (const float*)d_in[13];
  const float* g2   = (const float*)d_in[14];
  const float* be2  = (const float*)d_in[15];
  const float* W2   = (const float*)d_in[16];
  const float* b2   = (const float*)d_in[17];
  const float* Wfc  = (const float*)d_in[18];
  const float* bfc  = (const float*)d_in[19];
  float* outp = (float*)d_out;

  const size_t d16Bytes = 2ULL * 8192 * 4096 * 2;  // 134,217,728 per operator
  bool f16ok = ws_size >= (2 * d16Bytes + 4ULL * 1024 * 1024);
  char* wsB = (char*)d_ws;
  size_t off = f16ok ? 2 * d16Bytes : 0;
  unsigned short* Di16  = (unsigned short*)wsB;
  unsigned short* DiA16 = (unsigned short*)(wsB + d16Bytes);
  float* v = (float*)(wsB + off);            off += 2ULL * 1024 * 64 * 4;
  float* f = (float*)(wsB + off);            off += 2ULL * 2048 * 64 * 4;
  unsigned short* Xt = (unsigned short*)(wsB + off); off += 2ULL * 16 * 8192 * 2;
  float* pv = (float*)(wsB + off);           off += 32 * 128 * 4;
  float* pf = (float*)(wsB + off);           off += 32 * 128 * 4;
  float* pp = (float*)(wsB + off);           off += 128 * 128 * 4;

  // zero both 32x128 stat-partial buffers (contiguous); f itself needs no
  // memset anymore -- the first Di-bigmat runs with ZERO=1.
  (void)hipMemsetAsync(pv, 0, 2 * 32 * 128 * 4, stream);
  k_in<<<512, 256, 0, stream>>>(inp, Win, bin, v, pv);
  for (int i = 0; i < 5; i++) {
    k_transform<<<512, 256, 0, stream>>>(v, pv, g0 + i * 64, be0 + i * 64,
                                         W0 + i * 4096, b0 + i * 64, Xt, 2048, 4096);
    // Di-bigmat: writes f (+stats -> pf), zeroes pv for the upcoming DiA stats
    if (!f16ok) {
      if (i == 0)
        k_bigmat<0, 1><<<dim3(512, 2), 256, 0, stream>>>(Di, Di16, Xt, f, 8192, 4096, pf, pv);
      else
        k_bigmat<0, 0><<<dim3(512, 2), 256, 0, stream>>>(Di, Di16, Xt, f, 8192, 4096, pf, pv);
    } else if (i == 0) {
      k_bigmat<1, 1><<<dim3(512, 2), 256, 0, stream>>>(Di, Di16, Xt, f, 8192, 4096, pf, pv);
    } else {
      k_bigmat<2, 0><<<dim3(512, 2), 256, 0, stream>>>(Di, Di16, Xt, f, 8192, 4096, pf, pv);
    }

    k_transform<<<512, 256, 0, stream>>>(f, pf, g1 + i * 64, be1 + i * 64,
                                         W1 + i * 4096, b1 + i * 64, Xt, 4096, 8192);
    // DiA-bigmat: accumulates v (+stats -> pv), zeroes pf for next iteration
    if (!f16ok) {
      k_bigmat<0, 0><<<dim3(256, 2), 256, 0, stream>>>(DiA, DiA16, Xt, v, 4096, 8192, pv, pf);
    } else if (i == 0) {
      k_bigmat<1, 0><<<dim3(256, 2), 256, 0, stream>>>(DiA, DiA16, Xt, v, 4096, 8192, pv, pf);
    } else {
      k_bigmat<2, 0><<<dim3(256, 2), 256, 0, stream>>>(DiA, DiA16, Xt, v, 4096, 8192, pv, pf);
    }
  }
  k_trans_pool<<<128, 256, 0, stream>>>(v, pv, g2, be2, W2, b2, mask, pp);
  k_final<<<1, 256, 0, stream>>>(pp, mask, Wfc, bfc, outp);
}